// Round 19
// baseline (97.328 us; speedup 1.0000x reference)
//
#include <hip/hip_runtime.h>

#define D 8
#define EPS 1e-8f
#define LOG2E_OVER_TAU 2.8853900817779268f   // log2(e) / tau, tau = 0.5
#define LN2 0.6931471805599453f

// ---- pair-kernel geometry ----
#define NPAD 10240                     // N=10000 rounded up to ROWS_PER_BLOCK
#define WR 8                           // 16-row MFMA tiles per wave
#define ROWS_PER_WAVE (WR * 16)        // 128
#define ROWS_PER_BLOCK (ROWS_PER_WAVE * 4)  // 512 (4 waves)
#define JTPB 10                        // j-tiles per block: 63 y-blocks (62x10+5)
#define RSPAD 20                       // padded row stride (floats) for rs LDS tile
#define XB 20                          // x-blocks (NPAD/ROWS_PER_BLOCK)
#define YB 63                          // y-blocks (ceil(625/JTPB))

using f16x8 = __attribute__((ext_vector_type(8))) _Float16;
using f32x4 = __attribute__((ext_vector_type(4))) float;

__device__ __forceinline__ float fast_exp2(float x) {
    return __builtin_amdgcn_exp2f(x);
}

// Kernel 1: both projections per row, ELU, normalize.
// Outputs split-f16 operands for the MFMA pair kernel:
//   A = normalize(proj(z_mp)) * (log2e/tau)  -> Ah (f16 hi) + Al (f16 lo)
//   B = normalize(proj(z_sc))                -> Bh + Bl
// ldiag[i] = cos_ii / tau (f32 path). Zeroes out[0].
// Rows n in [N, NPAD) are zero-filled so MFMA pads give d=0 -> e=1
// (corrected via blockInv subtraction in the pair kernel).
// No rs/cs zeroing needed anymore: the pair kernel is atomic-free and
// every partial-buffer slot is written unconditionally.
__global__ void proj_kernel(const float* __restrict__ z1f,
                            const float* __restrict__ z2f,
                            const float* __restrict__ W1f,
                            const float* __restrict__ b1f,
                            const float* __restrict__ W2f,
                            const float* __restrict__ b2f,
                            f16x8* __restrict__ Ah, f16x8* __restrict__ Al,
                            f16x8* __restrict__ Bh, f16x8* __restrict__ Bl,
                            float* __restrict__ ldiag,
                            float* __restrict__ out,
                            int N) {
    int n = blockIdx.x * blockDim.x + threadIdx.x;
    if (n >= NPAD) return;
    if (n == 0) out[0] = 0.f;

    if (n >= N) {
        f16x8 z = {(_Float16)0.f, (_Float16)0.f, (_Float16)0.f, (_Float16)0.f,
                   (_Float16)0.f, (_Float16)0.f, (_Float16)0.f, (_Float16)0.f};
        Ah[n] = z; Al[n] = z; Bh[n] = z; Bl[n] = z;
        return;
    }

    float W1[D][D], W2[D][D], B1[D], B2[D];
#pragma unroll
    for (int k = 0; k < D; ++k) {
        B1[k] = b1f[k];
        B2[k] = b2f[k];
#pragma unroll
        for (int d2 = 0; d2 < D; ++d2) {
            W1[k][d2] = W1f[k * D + d2];
            W2[k][d2] = W2f[k * D + d2];
        }
    }

    const float4* z1v = (const float4*)z1f + 2 * n;
    const float4* z2v = (const float4*)z2f + 2 * n;
    float4 r1a = z1v[0], r1b = z1v[1];
    float4 r2a = z2v[0], r2b = z2v[1];
    float z1[D] = {r1a.x, r1a.y, r1a.z, r1a.w, r1b.x, r1b.y, r1b.z, r1b.w};
    float z2[D] = {r2a.x, r2a.y, r2a.z, r2a.w, r2b.x, r2b.y, r2b.z, r2b.w};

    float h1[D], h2[D];
#pragma unroll
    for (int k = 0; k < D; ++k) {
        float t1 = B1[k], t2 = B1[k];
#pragma unroll
        for (int d2 = 0; d2 < D; ++d2) {
            t1 = fmaf(z1[d2], W1[k][d2], t1);
            t2 = fmaf(z2[d2], W1[k][d2], t2);
        }
        h1[k] = (t1 > 0.f) ? t1 : (expf(t1) - 1.f);
        h2[k] = (t2 > 0.f) ? t2 : (expf(t2) - 1.f);
    }

    float p1[D], p2[D];
    float sq1 = 0.f, sq2 = 0.f;
#pragma unroll
    for (int o = 0; o < D; ++o) {
        float t1 = B2[o], t2 = B2[o];
#pragma unroll
        for (int k = 0; k < D; ++k) {
            t1 = fmaf(h1[k], W2[o][k], t1);
            t2 = fmaf(h2[k], W2[o][k], t2);
        }
        p1[o] = t1; p2[o] = t2;
        sq1 = fmaf(t1, t1, sq1);
        sq2 = fmaf(t2, t2, sq2);
    }
    float s1 = LOG2E_OVER_TAU * rsqrtf(sq1);
    float s2 = rsqrtf(sq2);

    f16x8 ah, al, bh, bl;
    float dacc = 0.f;
#pragma unroll
    for (int o = 0; o < D; ++o) {
        float av = p1[o] * s1;          // |a| <= 2.886
        float bv = p2[o] * s2;          // |b| <= 1
        dacc = fmaf(av, bv, dacc);
        _Float16 avh = (_Float16)av;
        _Float16 bvh = (_Float16)bv;
        ah[o] = avh;
        al[o] = (_Float16)(av - (float)avh);   // exact residual, then rounded
        bh[o] = bvh;
        bl[o] = (_Float16)(bv - (float)bvh);
    }
    Ah[n] = ah; Al[n] = al; Bh[n] = bh; Bl[n] = bl;
    ldiag[n] = dacc * LN2;   // log(diag_i) = cos_ii / tau
}

// Kernel 2: MFMA pair kernel — ATOMIC-FREE.
// Per wave: WR=8 16-row A tiles in registers, loop over <=JTPB 16-col j-tiles.
// One v_mfma_f32_16x16x32_f16 per (row-tile, j-tile) computes the split-
// precision dot (chunks by lane-group g: A [ah,al,ah,0], B [bh,bh,bl,0]
// => d = ah*bh + al*bh + ah*bl). C/D layout: col=lane&15, row=(lane>>4)*4+reg.
//
// Main loop: zero cross-lane ops (4 csum chains + 1 LDS write per jt).
// Epilogue (union'd 40 KB LDS, 3 barriers):
//   phase 1: cs reduce -> PLAIN STORE to cs_part[blockIdx.x][col] (each slot
//            written by exactly one block: y partitions the column range).
//   phase 2: rs transpose -> [512][RSPAD] LDS tile -> each thread sums 16
//            partials for 2 rows -> PLAIN STORE to rs_part[blockIdx.y][row]
//            (each slot written by exactly one block: x partitions rows).
// No global RMW anywhere -> no atomic serialization / waitcnt backpressure.
// Padded A-rows contribute e=exp2(0)=1 per column; corrected by subtracting
// blockInv in the cs store. B has no padded columns (nJT*16 == N).
__global__ __launch_bounds__(256) void pair_mfma_kernel(
        const f16x8* __restrict__ Ah, const f16x8* __restrict__ Al,
        const f16x8* __restrict__ Bh, const f16x8* __restrict__ Bl,
        float* __restrict__ rs_part,   // [YB][NPAD]
        float* __restrict__ cs_part,   // [XB][NPAD]
        int N, int nJT) {
    __shared__ float smem[ROWS_PER_BLOCK * RSPAD];   // 40960 B, union cs/rs

    int tid = threadIdx.x;
    int lane = tid & 63;
    int wave = tid >> 6;
    int c = lane & 15;          // col within tile (B), row within tile (A)
    int g = lane >> 4;          // k-chunk group
    int bbase = blockIdx.x * ROWS_PER_BLOCK;
    int wbase = bbase + wave * ROWS_PER_WAVE;

    // block-uniform count of padded rows in this block's 512-row span
    int binv = bbase + ROWS_PER_BLOCK - N;
    if (binv < 0) binv = 0;
    if (binv > ROWS_PER_BLOCK) binv = ROWS_PER_BLOCK;
    float blockInv = (float)binv;

    f16x8 kz = {(_Float16)0.f, (_Float16)0.f, (_Float16)0.f, (_Float16)0.f,
                (_Float16)0.f, (_Float16)0.f, (_Float16)0.f, (_Float16)0.f};

    // Load A fragments: row = wbase + t*16 + c (always < NPAD); chunk by group.
    const f16x8* Asrc = (g == 1) ? Al : Ah;   // g0,g2 -> hi; g1 -> lo; g3 -> 0
    f16x8 afrag[WR];
#pragma unroll
    for (int t = 0; t < WR; ++t) {
        afrag[t] = Asrc[wbase + t * 16 + c];
        if (g == 3) afrag[t] = kz;
    }

    float rsacc[WR][4];
#pragma unroll
    for (int t = 0; t < WR; ++t)
#pragma unroll
        for (int r = 0; r < 4; ++r) rsacc[t][r] = 0.f;

    int jt0 = blockIdx.y * JTPB;
    int jt1 = min(nJT, jt0 + JTPB);
    int jtCount = jt1 - jt0;                  // 10 (5 for the last y-block)

    const f16x8* Bsrc = (g == 2) ? Bl : Bh;   // g0,g1 -> hi; g2 -> lo; g3 -> 0
    f32x4 czero = {0.f, 0.f, 0.f, 0.f};

    f16x8 bcur = kz;
    if (g != 3) bcur = Bsrc[jt0 * 16 + c];

    for (int q = 0; q < jtCount; ++q) {
        // prefetch next tile's B fragment
        f16x8 bnext = bcur;
        if (q + 1 < jtCount && g != 3) bnext = Bsrc[(jt0 + q + 1) * 16 + c];

        float cs0 = 0.f, cs1 = 0.f, cs2 = 0.f, cs3 = 0.f;  // 4 chains, depth 8
#pragma unroll
        for (int t = 0; t < WR; ++t) {
            f32x4 dv = __builtin_amdgcn_mfma_f32_16x16x32_f16(
                afrag[t], bcur, czero, 0, 0, 0);
            float e0 = fast_exp2(dv[0]);
            float e1 = fast_exp2(dv[1]);
            float e2 = fast_exp2(dv[2]);
            float e3 = fast_exp2(dv[3]);
            rsacc[t][0] += e0; cs0 += e0;
            rsacc[t][1] += e1; cs1 += e1;
            rsacc[t][2] += e2; cs2 += e2;
            rsacc[t][3] += e3; cs3 += e3;
        }
        // one LDS write per jt: raw per-lane partial, no cross-lane ops
        smem[(wave * 4 + g) * (JTPB * 16) + q * 16 + c] =
            (cs0 + cs1) + (cs2 + cs3);

        bcur = bnext;
    }

    // ---- phase 1: cs reduce (16 partials per column -> 1 plain store) ----
    __syncthreads();
    int nEnt = jtCount * 16;                  // 160 (80 for tail y-block)
    float* csDst = cs_part + (size_t)blockIdx.x * NPAD + jt0 * 16;
    for (int e = tid; e < nEnt; e += 256) {
        float v = 0.f;
#pragma unroll
        for (int s = 0; s < 16; ++s) v += smem[s * (JTPB * 16) + e];
        csDst[e] = v - blockInv;
    }

    // ---- phase 2: rs transpose + coalesced reduce + plain store ----
    __syncthreads();                          // cs partials consumed; reuse smem
#pragma unroll
    for (int t = 0; t < WR; ++t) {
#pragma unroll
        for (int r = 0; r < 4; ++r) {
            int rowLoc = wave * ROWS_PER_WAVE + t * 16 + g * 4 + r;
            smem[rowLoc * RSPAD + c] = rsacc[t][r];
        }
    }
    __syncthreads();
    float* rsDst = rs_part + (size_t)blockIdx.y * NPAD + bbase;
#pragma unroll
    for (int rr = 0; rr < 2; ++rr) {
        int rowLoc = tid + rr * 256;
        const float4* rp = (const float4*)&smem[rowLoc * RSPAD];
        float4 a = rp[0], b = rp[1], cc = rp[2], dd = rp[3];
        float v = ((a.x + a.y) + (a.z + a.w)) + ((b.x + b.y) + (b.z + b.w))
                + ((cc.x + cc.y) + (cc.z + cc.w)) + ((dd.x + dd.y) + (dd.z + dd.w));
        rsDst[rowLoc] = v;                    // pad rows written, never read
    }
}

// Kernel 3: loss = mean_i[ 0.5*log(rs_i+eps) + 0.5*log(cs_i+eps) - ldiag_i ]
// rs_i = sum over YB y-partials; cs_i = sum over XB x-partials.
__global__ void finalize_kernel(const float* __restrict__ rs_part,
                                const float* __restrict__ cs_part,
                                const float* __restrict__ ldiag,
                                float* __restrict__ out,
                                int N) {
    int gid = blockIdx.x * blockDim.x + threadIdx.x;
    int stride = gridDim.x * blockDim.x;
    float acc = 0.f;
    for (int i = gid; i < N; i += stride) {
        float rsum = 0.f;
#pragma unroll 7
        for (int y = 0; y < YB; ++y) rsum += rs_part[(size_t)y * NPAD + i];
        float csum = 0.f;
#pragma unroll 5
        for (int x = 0; x < XB; ++x) csum += cs_part[(size_t)x * NPAD + i];
        acc += 0.5f * __logf(rsum + EPS) + 0.5f * __logf(csum + EPS) - ldiag[i];
    }
#pragma unroll
    for (int off = 32; off > 0; off >>= 1)
        acc += __shfl_down(acc, off, 64);
    __shared__ float wsum[4];
    int wave = threadIdx.x >> 6;
    if ((threadIdx.x & 63) == 0) wsum[wave] = acc;
    __syncthreads();
    if (threadIdx.x == 0) {
        float total = wsum[0] + wsum[1] + wsum[2] + wsum[3];
        atomicAdd(out, total / (float)N);
    }
}

extern "C" void kernel_launch(void* const* d_in, const int* in_sizes, int n_in,
                              void* d_out, int out_size, void* d_ws, size_t ws_size,
                              hipStream_t stream) {
    const float* z1 = (const float*)d_in[0];  // z_mp [N,8] f32
    const float* z2 = (const float*)d_in[1];  // z_sc [N,8] f32
    const float* W1 = (const float*)d_in[2];  // [8,8]
    const float* b1 = (const float*)d_in[3];  // [8]
    const float* W2 = (const float*)d_in[4];  // [8,8]
    const float* b2 = (const float*)d_in[5];  // [8]
    int N = in_sizes[0] / D;  // 10000

    // workspace: 4 split-f16 operand arrays + ldiag + rs_part[YB] + cs_part[XB]
    f16x8* Ah = (f16x8*)d_ws;
    f16x8* Al = Ah + NPAD;
    f16x8* Bh = Al + NPAD;
    f16x8* Bl = Bh + NPAD;
    float* ldiag = (float*)(Bl + NPAD);
    float* rs_part = ldiag + NPAD;                     // YB * NPAD
    float* cs_part = rs_part + (size_t)YB * NPAD;      // XB * NPAD
    float* out = (float*)d_out;

    proj_kernel<<<NPAD / 256, 256, 0, stream>>>(z1, z2, W1, b1, W2, b2,
                                                Ah, Al, Bh, Bl,
                                                ldiag, out, N);

    int nJT = N / 16;                           // 625 (16-aligned)
    dim3 pgrid(XB, YB);                         // 1260 blocks, 5040 waves
    pair_mfma_kernel<<<pgrid, 256, 0, stream>>>(Ah, Al, Bh, Bl,
                                                rs_part, cs_part, N, nJT);

    finalize_kernel<<<20, 256, 0, stream>>>(rs_part, cs_part, ldiag, out, N);
}

// Round 20
// 93.558 us; speedup vs baseline: 1.0403x; 1.0403x over previous
//
#include <hip/hip_runtime.h>

#define D 8
#define EPS 1e-8f
#define LOG2E_OVER_TAU 2.8853900817779268f   // log2(e) / tau, tau = 0.5
#define LN2 0.6931471805599453f

// ---- pair-kernel geometry ----
#define NPAD 10240                     // N=10000 rounded up to ROWS_PER_BLOCK
#define WR 8                           // 16-row MFMA tiles per wave
#define ROWS_PER_WAVE (WR * 16)        // 128
#define ROWS_PER_BLOCK (ROWS_PER_WAVE * 4)  // 512 (4 waves)
#define JTPB 21                        // j-tiles per block: 30 y-blocks (29x21+16)
#define RSPAD 20                       // padded row stride (floats) for rs LDS tile

using f16x8 = __attribute__((ext_vector_type(8))) _Float16;
using f32x4 = __attribute__((ext_vector_type(4))) float;

__device__ __forceinline__ float fast_exp2(float x) {
    return __builtin_amdgcn_exp2f(x);
}

// Kernel 1: both projections per row, ELU, normalize.
// Outputs split-f16 operands for the MFMA pair kernel:
//   A = normalize(proj(z_mp)) * (log2e/tau)  -> Ah (f16 hi) + Al (f16 lo)
//   B = normalize(proj(z_sc))                -> Bh + Bl
// ldiag[i] = cos_ii / tau (f32 path). Also zeroes rs/cs/out (replaces memsets).
// Rows n in [N, NPAD) are zero-filled so MFMA pads give d=0 -> e=1
// (corrected via blockInv subtraction in the pair kernel).
__global__ void proj_kernel(const float* __restrict__ z1f,
                            const float* __restrict__ z2f,
                            const float* __restrict__ W1f,
                            const float* __restrict__ b1f,
                            const float* __restrict__ W2f,
                            const float* __restrict__ b2f,
                            f16x8* __restrict__ Ah, f16x8* __restrict__ Al,
                            f16x8* __restrict__ Bh, f16x8* __restrict__ Bl,
                            float* __restrict__ ldiag,
                            float* __restrict__ rs,
                            float* __restrict__ cs,
                            float* __restrict__ out,
                            int N) {
    int n = blockIdx.x * blockDim.x + threadIdx.x;
    if (n >= NPAD) return;
    rs[n] = 0.f;
    cs[n] = 0.f;
    if (n == 0) out[0] = 0.f;

    if (n >= N) {
        f16x8 z = {(_Float16)0.f, (_Float16)0.f, (_Float16)0.f, (_Float16)0.f,
                   (_Float16)0.f, (_Float16)0.f, (_Float16)0.f, (_Float16)0.f};
        Ah[n] = z; Al[n] = z; Bh[n] = z; Bl[n] = z;
        return;
    }

    float W1[D][D], W2[D][D], B1[D], B2[D];
#pragma unroll
    for (int k = 0; k < D; ++k) {
        B1[k] = b1f[k];
        B2[k] = b2f[k];
#pragma unroll
        for (int d2 = 0; d2 < D; ++d2) {
            W1[k][d2] = W1f[k * D + d2];
            W2[k][d2] = W2f[k * D + d2];
        }
    }

    const float4* z1v = (const float4*)z1f + 2 * n;
    const float4* z2v = (const float4*)z2f + 2 * n;
    float4 r1a = z1v[0], r1b = z1v[1];
    float4 r2a = z2v[0], r2b = z2v[1];
    float z1[D] = {r1a.x, r1a.y, r1a.z, r1a.w, r1b.x, r1b.y, r1b.z, r1b.w};
    float z2[D] = {r2a.x, r2a.y, r2a.z, r2a.w, r2b.x, r2b.y, r2b.z, r2b.w};

    float h1[D], h2[D];
#pragma unroll
    for (int k = 0; k < D; ++k) {
        float t1 = B1[k], t2 = B1[k];
#pragma unroll
        for (int d2 = 0; d2 < D; ++d2) {
            t1 = fmaf(z1[d2], W1[k][d2], t1);
            t2 = fmaf(z2[d2], W1[k][d2], t2);
        }
        h1[k] = (t1 > 0.f) ? t1 : (expf(t1) - 1.f);
        h2[k] = (t2 > 0.f) ? t2 : (expf(t2) - 1.f);
    }

    float p1[D], p2[D];
    float sq1 = 0.f, sq2 = 0.f;
#pragma unroll
    for (int o = 0; o < D; ++o) {
        float t1 = B2[o], t2 = B2[o];
#pragma unroll
        for (int k = 0; k < D; ++k) {
            t1 = fmaf(h1[k], W2[o][k], t1);
            t2 = fmaf(h2[k], W2[o][k], t2);
        }
        p1[o] = t1; p2[o] = t2;
        sq1 = fmaf(t1, t1, sq1);
        sq2 = fmaf(t2, t2, sq2);
    }
    float s1 = LOG2E_OVER_TAU * rsqrtf(sq1);
    float s2 = rsqrtf(sq2);

    f16x8 ah, al, bh, bl;
    float dacc = 0.f;
#pragma unroll
    for (int o = 0; o < D; ++o) {
        float av = p1[o] * s1;          // |a| <= 2.886
        float bv = p2[o] * s2;          // |b| <= 1
        dacc = fmaf(av, bv, dacc);
        _Float16 avh = (_Float16)av;
        _Float16 bvh = (_Float16)bv;
        ah[o] = avh;
        al[o] = (_Float16)(av - (float)avh);   // exact residual, then rounded
        bh[o] = bvh;
        bl[o] = (_Float16)(bv - (float)bvh);
    }
    Ah[n] = ah; Al[n] = al; Bh[n] = bh; Bl[n] = bl;
    ldiag[n] = dacc * LN2;   // log(diag_i) = cos_ii / tau
}

// Kernel 2: MFMA pair kernel (R18 structure, JTPB=21).
// Per wave: WR=8 16-row A tiles in registers, loop over <=JTPB 16-col j-tiles.
// One v_mfma_f32_16x16x32_f16 per (row-tile, j-tile) computes the split-
// precision dot (chunks by lane-group g: A [ah,al,ah,0], B [bh,bh,bl,0]
// => d = ah*bh + al*bh + ah*bl). C/D layout: col=lane&15, row=(lane>>4)*4+reg.
//
// Main loop has ZERO cross-lane ops: per jt, each lane accumulates csum into
// 4 independent partials (chain depth 8, not 32) and does 1 LDS write.
// Epilogue (union'd 40 KB LDS buffer, 3 barriers):
//   phase 1: cs reduce — 16 partials/column summed, 1 coalesced atomic each.
//   phase 2: rs transpose — rsacc -> [512][RSPAD] LDS tile, then each thread
//            sums 16 partials for 2 rows and issues 2 coalesced atomics.
// Padded rows contribute e=exp2(0)=1 per column; corrected by subtracting
// the block-uniform pad count (blockInv) once per column in the cs reduce.
// JTPB=21 -> 600 blocks: all-resident (4 blocks/CU LDS cap), 2.1x longer
// main loop amortizing per-block ramp (launch, A-prologue, epilogue).
__global__ __launch_bounds__(256) void pair_mfma_kernel(
        const f16x8* __restrict__ Ah, const f16x8* __restrict__ Al,
        const f16x8* __restrict__ Bh, const f16x8* __restrict__ Bl,
        float* __restrict__ rs,
        float* __restrict__ cs,
        int N, int nJT) {
    __shared__ float smem[ROWS_PER_BLOCK * RSPAD];   // 40960 B, union cs/rs
    // cs phase uses 16 * (JTPB*16) = 5376 floats <= 10240 ✓

    int tid = threadIdx.x;
    int lane = tid & 63;
    int wave = tid >> 6;
    int c = lane & 15;          // col within tile (B), row within tile (A)
    int g = lane >> 4;          // k-chunk group
    int bbase = blockIdx.x * ROWS_PER_BLOCK;
    int wbase = bbase + wave * ROWS_PER_WAVE;

    // block-uniform count of padded rows in this block's 512-row span
    int binv = bbase + ROWS_PER_BLOCK - N;
    if (binv < 0) binv = 0;
    if (binv > ROWS_PER_BLOCK) binv = ROWS_PER_BLOCK;
    float blockInv = (float)binv;

    f16x8 kz = {(_Float16)0.f, (_Float16)0.f, (_Float16)0.f, (_Float16)0.f,
                (_Float16)0.f, (_Float16)0.f, (_Float16)0.f, (_Float16)0.f};

    // Load A fragments: row = wbase + t*16 + c (always < NPAD); chunk by group.
    const f16x8* Asrc = (g == 1) ? Al : Ah;   // g0,g2 -> hi; g1 -> lo; g3 -> 0
    f16x8 afrag[WR];
#pragma unroll
    for (int t = 0; t < WR; ++t) {
        afrag[t] = Asrc[wbase + t * 16 + c];
        if (g == 3) afrag[t] = kz;
    }

    float rsacc[WR][4];
#pragma unroll
    for (int t = 0; t < WR; ++t)
#pragma unroll
        for (int r = 0; r < 4; ++r) rsacc[t][r] = 0.f;

    int jt0 = blockIdx.y * JTPB;
    int jt1 = min(nJT, jt0 + JTPB);
    int jtCount = jt1 - jt0;                  // 21 (16 for the last y-block)

    const f16x8* Bsrc = (g == 2) ? Bl : Bh;   // g0,g1 -> hi; g2 -> lo; g3 -> 0
    f32x4 czero = {0.f, 0.f, 0.f, 0.f};

    f16x8 bcur = kz;
    if (g != 3) bcur = Bsrc[jt0 * 16 + c];

    for (int q = 0; q < jtCount; ++q) {
        // prefetch next tile's B fragment
        f16x8 bnext = bcur;
        if (q + 1 < jtCount && g != 3) bnext = Bsrc[(jt0 + q + 1) * 16 + c];

        float cs0 = 0.f, cs1 = 0.f, cs2 = 0.f, cs3 = 0.f;  // 4 chains, depth 8
#pragma unroll
        for (int t = 0; t < WR; ++t) {
            f32x4 dv = __builtin_amdgcn_mfma_f32_16x16x32_f16(
                afrag[t], bcur, czero, 0, 0, 0);
            float e0 = fast_exp2(dv[0]);
            float e1 = fast_exp2(dv[1]);
            float e2 = fast_exp2(dv[2]);
            float e3 = fast_exp2(dv[3]);
            rsacc[t][0] += e0; cs0 += e0;
            rsacc[t][1] += e1; cs1 += e1;
            rsacc[t][2] += e2; cs2 += e2;
            rsacc[t][3] += e3; cs3 += e3;
        }
        // one LDS write per jt: raw per-lane partial, no cross-lane ops
        smem[(wave * 4 + g) * (JTPB * 16) + q * 16 + c] =
            (cs0 + cs1) + (cs2 + cs3);

        bcur = bnext;
    }

    // ---- phase 1: cs reduce (16 partials per column -> 1 atomic) ----
    __syncthreads();
    int nEnt = jtCount * 16;                  // 336 (256 for tail y-block)
    for (int e = tid; e < nEnt; e += 256) {
        float v = 0.f;
#pragma unroll
        for (int s = 0; s < 16; ++s) v += smem[s * (JTPB * 16) + e];
        atomicAdd(&cs[jt0 * 16 + e], v - blockInv);
    }

    // ---- phase 2: rs transpose + coalesced reduce ----
    __syncthreads();                          // cs partials consumed; reuse smem
#pragma unroll
    for (int t = 0; t < WR; ++t) {
#pragma unroll
        for (int r = 0; r < 4; ++r) {
            int rowLoc = wave * ROWS_PER_WAVE + t * 16 + g * 4 + r;
            smem[rowLoc * RSPAD + c] = rsacc[t][r];
        }
    }
    __syncthreads();
#pragma unroll
    for (int rr = 0; rr < 2; ++rr) {
        int rowLoc = tid + rr * 256;
        const float4* rp = (const float4*)&smem[rowLoc * RSPAD];
        float4 a = rp[0], b = rp[1], cc = rp[2], dd = rp[3];
        float v = ((a.x + a.y) + (a.z + a.w)) + ((b.x + b.y) + (b.z + b.w))
                + ((cc.x + cc.y) + (cc.z + cc.w)) + ((dd.x + dd.y) + (dd.z + dd.w));
        int row = bbase + rowLoc;
        if (row < N) atomicAdd(&rs[row], v);
    }
}

// Kernel 3: loss = mean_i[ 0.5*log(rs_i+eps) + 0.5*log(cs_i+eps) - ldiag_i ]
__global__ void finalize_kernel(const float* __restrict__ rs,
                                const float* __restrict__ cs,
                                const float* __restrict__ ldiag,
                                float* __restrict__ out,
                                int N) {
    int gid = blockIdx.x * blockDim.x + threadIdx.x;
    int stride = gridDim.x * blockDim.x;
    float acc = 0.f;
    for (int i = gid; i < N; i += stride) {
        acc += 0.5f * __logf(rs[i] + EPS) + 0.5f * __logf(cs[i] + EPS) - ldiag[i];
    }
#pragma unroll
    for (int off = 32; off > 0; off >>= 1)
        acc += __shfl_down(acc, off, 64);
    __shared__ float wsum[4];
    int wave = threadIdx.x >> 6;
    if ((threadIdx.x & 63) == 0) wsum[wave] = acc;
    __syncthreads();
    if (threadIdx.x == 0) {
        float total = wsum[0] + wsum[1] + wsum[2] + wsum[3];
        atomicAdd(out, total / (float)N);
    }
}

extern "C" void kernel_launch(void* const* d_in, const int* in_sizes, int n_in,
                              void* d_out, int out_size, void* d_ws, size_t ws_size,
                              hipStream_t stream) {
    const float* z1 = (const float*)d_in[0];  // z_mp [N,8] f32
    const float* z2 = (const float*)d_in[1];  // z_sc [N,8] f32
    const float* W1 = (const float*)d_in[2];  // [8,8]
    const float* b1 = (const float*)d_in[3];  // [8]
    const float* W2 = (const float*)d_in[4];  // [8,8]
    const float* b2 = (const float*)d_in[5];  // [8]
    int N = in_sizes[0] / D;  // 10000

    // workspace layout: 4 split-f16 operand arrays (NPAD rows x 16B) + 3 f32
    f16x8* Ah = (f16x8*)d_ws;
    f16x8* Al = Ah + NPAD;
    f16x8* Bh = Al + NPAD;
    f16x8* Bl = Bh + NPAD;
    float* ldiag = (float*)(Bl + NPAD);
    float* rs = ldiag + NPAD;
    float* cs = rs + NPAD;
    float* out = (float*)d_out;

    proj_kernel<<<NPAD / 256, 256, 0, stream>>>(z1, z2, W1, b1, W2, b2,
                                                Ah, Al, Bh, Bl,
                                                ldiag, rs, cs, out, N);

    int iBlocks = NPAD / ROWS_PER_BLOCK;        // 20
    int nJT = N / 16;                           // 625 (16-aligned)
    int yBlocks = (nJT + JTPB - 1) / JTPB;      // 30 (29x21 + 16)
    dim3 pgrid(iBlocks, yBlocks);               // 600 blocks, 2400 waves
    pair_mfma_kernel<<<pgrid, 256, 0, stream>>>(Ah, Al, Bh, Bl, rs, cs,
                                                N, nJT);

    finalize_kernel<<<10, 256, 0, stream>>>(rs, cs, ldiag, out, N);
}

// Round 21
// 87.736 us; speedup vs baseline: 1.1093x; 1.0664x over previous
//
#include <hip/hip_runtime.h>

#define D 8
#define EPS 1e-8f
#define LOG2E_OVER_TAU 2.8853900817779268f   // log2(e) / tau, tau = 0.5
#define LN2 0.6931471805599453f

// ---- pair-kernel geometry ----
#define NPAD 10240                     // N=10000 rounded up to ROWS_PER_BLOCK
#define WR 8                           // 16-row MFMA tiles per wave
#define ROWS_PER_WAVE (WR * 16)        // 128
#define ROWS_PER_BLOCK (ROWS_PER_WAVE * 4)  // 512 (4 waves)
#define JTPB 10                        // j-tiles per block: 63 y-blocks (62x10+5)
#define RSPAD 20                       // padded row stride (floats) for rs LDS tile
#define HALF_ROWS 256                  // rows per rs-transpose pass (2 waves)

using f16x8 = __attribute__((ext_vector_type(8))) _Float16;
using f32x4 = __attribute__((ext_vector_type(4))) float;

__device__ __forceinline__ float fast_exp2(float x) {
    return __builtin_amdgcn_exp2f(x);
}

// Kernel 1: both projections per row, ELU, normalize.
// Outputs split-f16 operands for the MFMA pair kernel:
//   A = normalize(proj(z_mp)) * (log2e/tau)  -> Ah (f16 hi) + Al (f16 lo)
//   B = normalize(proj(z_sc))                -> Bh + Bl
// ldiag[i] = cos_ii / tau (f32 path). Also zeroes rs/cs/out (replaces memsets).
// Rows n in [N, NPAD) are zero-filled so MFMA pads give d=0 -> e=1
// (corrected via blockInv subtraction in the pair kernel).
__global__ void proj_kernel(const float* __restrict__ z1f,
                            const float* __restrict__ z2f,
                            const float* __restrict__ W1f,
                            const float* __restrict__ b1f,
                            const float* __restrict__ W2f,
                            const float* __restrict__ b2f,
                            f16x8* __restrict__ Ah, f16x8* __restrict__ Al,
                            f16x8* __restrict__ Bh, f16x8* __restrict__ Bl,
                            float* __restrict__ ldiag,
                            float* __restrict__ rs,
                            float* __restrict__ cs,
                            float* __restrict__ out,
                            int N) {
    int n = blockIdx.x * blockDim.x + threadIdx.x;
    if (n >= NPAD) return;
    rs[n] = 0.f;
    cs[n] = 0.f;
    if (n == 0) out[0] = 0.f;

    if (n >= N) {
        f16x8 z = {(_Float16)0.f, (_Float16)0.f, (_Float16)0.f, (_Float16)0.f,
                   (_Float16)0.f, (_Float16)0.f, (_Float16)0.f, (_Float16)0.f};
        Ah[n] = z; Al[n] = z; Bh[n] = z; Bl[n] = z;
        return;
    }

    float W1[D][D], W2[D][D], B1[D], B2[D];
#pragma unroll
    for (int k = 0; k < D; ++k) {
        B1[k] = b1f[k];
        B2[k] = b2f[k];
#pragma unroll
        for (int d2 = 0; d2 < D; ++d2) {
            W1[k][d2] = W1f[k * D + d2];
            W2[k][d2] = W2f[k * D + d2];
        }
    }

    const float4* z1v = (const float4*)z1f + 2 * n;
    const float4* z2v = (const float4*)z2f + 2 * n;
    float4 r1a = z1v[0], r1b = z1v[1];
    float4 r2a = z2v[0], r2b = z2v[1];
    float z1[D] = {r1a.x, r1a.y, r1a.z, r1a.w, r1b.x, r1b.y, r1b.z, r1b.w};
    float z2[D] = {r2a.x, r2a.y, r2a.z, r2a.w, r2b.x, r2b.y, r2b.z, r2b.w};

    float h1[D], h2[D];
#pragma unroll
    for (int k = 0; k < D; ++k) {
        float t1 = B1[k], t2 = B1[k];
#pragma unroll
        for (int d2 = 0; d2 < D; ++d2) {
            t1 = fmaf(z1[d2], W1[k][d2], t1);
            t2 = fmaf(z2[d2], W1[k][d2], t2);
        }
        h1[k] = (t1 > 0.f) ? t1 : (expf(t1) - 1.f);
        h2[k] = (t2 > 0.f) ? t2 : (expf(t2) - 1.f);
    }

    float p1[D], p2[D];
    float sq1 = 0.f, sq2 = 0.f;
#pragma unroll
    for (int o = 0; o < D; ++o) {
        float t1 = B2[o], t2 = B2[o];
#pragma unroll
        for (int k = 0; k < D; ++k) {
            t1 = fmaf(h1[k], W2[o][k], t1);
            t2 = fmaf(h2[k], W2[o][k], t2);
        }
        p1[o] = t1; p2[o] = t2;
        sq1 = fmaf(t1, t1, sq1);
        sq2 = fmaf(t2, t2, sq2);
    }
    float s1 = LOG2E_OVER_TAU * rsqrtf(sq1);
    float s2 = rsqrtf(sq2);

    f16x8 ah, al, bh, bl;
    float dacc = 0.f;
#pragma unroll
    for (int o = 0; o < D; ++o) {
        float av = p1[o] * s1;          // |a| <= 2.886
        float bv = p2[o] * s2;          // |b| <= 1
        dacc = fmaf(av, bv, dacc);
        _Float16 avh = (_Float16)av;
        _Float16 bvh = (_Float16)bv;
        ah[o] = avh;
        al[o] = (_Float16)(av - (float)avh);   // exact residual, then rounded
        bh[o] = bvh;
        bl[o] = (_Float16)(bv - (float)bvh);
    }
    Ah[n] = ah; Al[n] = al; Bh[n] = bh; Bl[n] = bl;
    ldiag[n] = dacc * LN2;   // log(diag_i) = cos_ii / tau
}

// Kernel 2: MFMA pair kernel (R18 structure, 20 KB LDS for full residency).
// Per wave: WR=8 16-row A tiles in registers, loop over <=JTPB 16-col j-tiles.
// One v_mfma_f32_16x16x32_f16 per (row-tile, j-tile) computes the split-
// precision dot (chunks by lane-group g: A [ah,al,ah,0], B [bh,bh,bl,0]
// => d = ah*bh + al*bh + ah*bl). C/D layout: col=lane&15, row=(lane>>4)*4+reg.
//
// Main loop has ZERO cross-lane ops: per jt, each lane accumulates csum into
// 4 independent partials (chain depth 8, not 32) and does 1 LDS write.
// Epilogue (20 KB union'd LDS):
//   phase 1: cs reduce — 16 partials/column summed, 1 coalesced atomic each.
//   phase 2: rs transpose in TWO 256-row passes (waves 0-1 then waves 2-3
//            write their rsacc; all 256 threads reduce one row each and issue
//            1 coalesced atomic). Halving the tile 512->256 rows cuts LDS
//            40 KB -> 20 KB, so the binding occupancy cap moves from LDS
//            (4 blocks/CU) to VGPR (5 blocks/CU) -> all 1260 blocks resident,
//            20 waves/CU vs 16 (+25% TLP vs the 89.3 us R18 version).
// Padded rows contribute e=exp2(0)=1 per column; corrected by subtracting
// the block-uniform pad count (blockInv) once per column in the cs reduce.
__global__ __launch_bounds__(256) void pair_mfma_kernel(
        const f16x8* __restrict__ Ah, const f16x8* __restrict__ Al,
        const f16x8* __restrict__ Bh, const f16x8* __restrict__ Bl,
        float* __restrict__ rs,
        float* __restrict__ cs,
        int N, int nJT) {
    __shared__ float smem[HALF_ROWS * RSPAD];   // 20480 B, union cs/rs
    // cs phase uses 16 * (JTPB*16) = 2560 floats <= 5120 ✓

    int tid = threadIdx.x;
    int lane = tid & 63;
    int wave = tid >> 6;
    int c = lane & 15;          // col within tile (B), row within tile (A)
    int g = lane >> 4;          // k-chunk group
    int bbase = blockIdx.x * ROWS_PER_BLOCK;
    int wbase = bbase + wave * ROWS_PER_WAVE;

    // block-uniform count of padded rows in this block's 512-row span
    int binv = bbase + ROWS_PER_BLOCK - N;
    if (binv < 0) binv = 0;
    if (binv > ROWS_PER_BLOCK) binv = ROWS_PER_BLOCK;
    float blockInv = (float)binv;

    f16x8 kz = {(_Float16)0.f, (_Float16)0.f, (_Float16)0.f, (_Float16)0.f,
                (_Float16)0.f, (_Float16)0.f, (_Float16)0.f, (_Float16)0.f};

    // Load A fragments: row = wbase + t*16 + c (always < NPAD); chunk by group.
    const f16x8* Asrc = (g == 1) ? Al : Ah;   // g0,g2 -> hi; g1 -> lo; g3 -> 0
    f16x8 afrag[WR];
#pragma unroll
    for (int t = 0; t < WR; ++t) {
        afrag[t] = Asrc[wbase + t * 16 + c];
        if (g == 3) afrag[t] = kz;
    }

    float rsacc[WR][4];
#pragma unroll
    for (int t = 0; t < WR; ++t)
#pragma unroll
        for (int r = 0; r < 4; ++r) rsacc[t][r] = 0.f;

    int jt0 = blockIdx.y * JTPB;
    int jt1 = min(nJT, jt0 + JTPB);
    int jtCount = jt1 - jt0;                  // 10 (5 for the last y-block)

    const f16x8* Bsrc = (g == 2) ? Bl : Bh;   // g0,g1 -> hi; g2 -> lo; g3 -> 0
    f32x4 czero = {0.f, 0.f, 0.f, 0.f};

    f16x8 bcur = kz;
    if (g != 3) bcur = Bsrc[jt0 * 16 + c];

    for (int q = 0; q < jtCount; ++q) {
        // prefetch next tile's B fragment
        f16x8 bnext = bcur;
        if (q + 1 < jtCount && g != 3) bnext = Bsrc[(jt0 + q + 1) * 16 + c];

        float cs0 = 0.f, cs1 = 0.f, cs2 = 0.f, cs3 = 0.f;  // 4 chains, depth 8
#pragma unroll
        for (int t = 0; t < WR; ++t) {
            f32x4 dv = __builtin_amdgcn_mfma_f32_16x16x32_f16(
                afrag[t], bcur, czero, 0, 0, 0);
            float e0 = fast_exp2(dv[0]);
            float e1 = fast_exp2(dv[1]);
            float e2 = fast_exp2(dv[2]);
            float e3 = fast_exp2(dv[3]);
            rsacc[t][0] += e0; cs0 += e0;
            rsacc[t][1] += e1; cs1 += e1;
            rsacc[t][2] += e2; cs2 += e2;
            rsacc[t][3] += e3; cs3 += e3;
        }
        // one LDS write per jt: raw per-lane partial, no cross-lane ops
        smem[(wave * 4 + g) * (JTPB * 16) + q * 16 + c] =
            (cs0 + cs1) + (cs2 + cs3);

        bcur = bnext;
    }

    // ---- phase 1: cs reduce (16 partials per column -> 1 atomic) ----
    __syncthreads();
    int nEnt = jtCount * 16;                  // 160 (80 for tail y-block)
    for (int e = tid; e < nEnt; e += 256) {
        float v = 0.f;
#pragma unroll
        for (int s = 0; s < 16; ++s) v += smem[s * (JTPB * 16) + e];
        atomicAdd(&cs[jt0 * 16 + e], v - blockInv);
    }

    // ---- phase 2: rs transpose + coalesced reduce, two 256-row passes ----
#pragma unroll
    for (int pass = 0; pass < 2; ++pass) {
        __syncthreads();                      // prev contents consumed
        if ((wave >> 1) == pass) {            // waves {0,1} then {2,3}
#pragma unroll
            for (int t = 0; t < WR; ++t) {
#pragma unroll
                for (int r = 0; r < 4; ++r) {
                    int rowLoc = (wave & 1) * ROWS_PER_WAVE + t * 16 + g * 4 + r;
                    smem[rowLoc * RSPAD + c] = rsacc[t][r];
                }
            }
        }
        __syncthreads();
        const float4* rp = (const float4*)&smem[tid * RSPAD];
        float4 a = rp[0], b = rp[1], cc = rp[2], dd = rp[3];
        float v = ((a.x + a.y) + (a.z + a.w)) + ((b.x + b.y) + (b.z + b.w))
                + ((cc.x + cc.y) + (cc.z + cc.w)) + ((dd.x + dd.y) + (dd.z + dd.w));
        int row = bbase + pass * HALF_ROWS + tid;
        if (row < N) atomicAdd(&rs[row], v);
    }
}

// Kernel 3: loss = mean_i[ 0.5*log(rs_i+eps) + 0.5*log(cs_i+eps) - ldiag_i ]
__global__ void finalize_kernel(const float* __restrict__ rs,
                                const float* __restrict__ cs,
                                const float* __restrict__ ldiag,
                                float* __restrict__ out,
                                int N) {
    int gid = blockIdx.x * blockDim.x + threadIdx.x;
    int stride = gridDim.x * blockDim.x;
    float acc = 0.f;
    for (int i = gid; i < N; i += stride) {
        acc += 0.5f * __logf(rs[i] + EPS) + 0.5f * __logf(cs[i] + EPS) - ldiag[i];
    }
#pragma unroll
    for (int off = 32; off > 0; off >>= 1)
        acc += __shfl_down(acc, off, 64);
    __shared__ float wsum[4];
    int wave = threadIdx.x >> 6;
    if ((threadIdx.x & 63) == 0) wsum[wave] = acc;
    __syncthreads();
    if (threadIdx.x == 0) {
        float total = wsum[0] + wsum[1] + wsum[2] + wsum[3];
        atomicAdd(out, total / (float)N);
    }
}

extern "C" void kernel_launch(void* const* d_in, const int* in_sizes, int n_in,
                              void* d_out, int out_size, void* d_ws, size_t ws_size,
                              hipStream_t stream) {
    const float* z1 = (const float*)d_in[0];  // z_mp [N,8] f32
    const float* z2 = (const float*)d_in[1];  // z_sc [N,8] f32
    const float* W1 = (const float*)d_in[2];  // [8,8]
    const float* b1 = (const float*)d_in[3];  // [8]
    const float* W2 = (const float*)d_in[4];  // [8,8]
    const float* b2 = (const float*)d_in[5];  // [8]
    int N = in_sizes[0] / D;  // 10000

    // workspace layout: 4 split-f16 operand arrays (NPAD rows x 16B) + 3 f32
    f16x8* Ah = (f16x8*)d_ws;
    f16x8* Al = Ah + NPAD;
    f16x8* Bh = Al + NPAD;
    f16x8* Bl = Bh + NPAD;
    float* ldiag = (float*)(Bl + NPAD);
    float* rs = ldiag + NPAD;
    float* cs = rs + NPAD;
    float* out = (float*)d_out;

    proj_kernel<<<NPAD / 256, 256, 0, stream>>>(z1, z2, W1, b1, W2, b2,
                                                Ah, Al, Bh, Bl,
                                                ldiag, rs, cs, out, N);

    int iBlocks = NPAD / ROWS_PER_BLOCK;        // 20
    int nJT = N / 16;                           // 625 (16-aligned)
    int yBlocks = (nJT + JTPB - 1) / JTPB;      // 63 (62x10 + 5)
    dim3 pgrid(iBlocks, yBlocks);               // 1260 blocks, 5040 waves
    pair_mfma_kernel<<<pgrid, 256, 0, stream>>>(Ah, Al, Bh, Bl, rs, cs,
                                                N, nJT);

    finalize_kernel<<<10, 256, 0, stream>>>(rs, cs, ldiag, out, N);
}